// Round 4
// baseline (230.095 us; speedup 1.0000x reference)
//
#include <hip/hip_runtime.h>

// SimpleRetention on MI355X (gfx950), bf16 MFMA path.
// ret = (S * sigmoid(S)) @ V,  S = (Q K^T) * gamma^|n-m|
// B=8, S=2048, H=512, gamma = 31/32. Decay band truncated at +-256..319
// (gamma^256 ~ 2.9e-4 -> contribution << 2%-of-absmax threshold).
//
// v3: attn software-pipelined. Structural fact: 16384 q-rows / 16-per-wave
// = 1024 waves = 1 wave/SIMD -> no TLP. So overlap within the wave: each
// barrier-free region holds STAGE_K(t+1) || PV(t-1) || QK(t) (independent),
// with double-buffered Kbuf and double-buffered wave-private P. One barrier
// per iteration (Kbuf WAR + stage drain, covered by the whole body).

typedef short  bf16x8 __attribute__((ext_vector_type(8)));
typedef float  f32x4  __attribute__((ext_vector_type(4)));

constexpr int S_LEN = 2048;
constexpr int HID   = 512;
constexpr int BAND  = 256;

#define GAMMA_L2 (-0.045803689613125f)   /* log2(31/32) */
#define LOG2E    (1.4426950408889634f)

__device__ __forceinline__ ushort f2bf(float f) {
  union { float f; unsigned u; } v; v.f = f;
  unsigned u = v.u;
  u += 0x7FFFu + ((u >> 16) & 1u);      // RNE, matches v_cvt
  return (ushort)(u >> 16);
}

__device__ __forceinline__ void gld_lds16(const ushort* g, ushort* l) {
  __builtin_amdgcn_global_load_lds(
      (const __attribute__((address_space(1))) void*)g,
      (__attribute__((address_space(3))) void*)l, 16, 0, 0);
}

// ---------------------------------------------------------------- cvt X -> bf16
__global__ void cvt_x_kernel(const float* __restrict__ X, ushort* __restrict__ Xb) {
  const int n4 = (8 * S_LEN * HID) / 4;
  int i = blockIdx.x * blockDim.x + threadIdx.x;
  const int stride = gridDim.x * blockDim.x;
  for (; i < n4; i += stride) {
    float4 v = ((const float4*)X)[i];
    ushort4 o;
    o.x = f2bf(v.x); o.y = f2bf(v.y); o.z = f2bf(v.z); o.w = f2bf(v.w);
    ((ushort4*)Xb)[i] = o;
  }
}

// ------------------------------------------------ cvt + transpose W -> Wt bf16
// Wtb[mat][n][k] = W_mat[k][n]  (so GEMM B-fragments are contiguous along K)
__global__ void cvt_w_kernel(const float* __restrict__ Wq, const float* __restrict__ Wk,
                             const float* __restrict__ Wv, ushort* __restrict__ Wtb) {
  __shared__ float tile[64][65];
  const int mat = blockIdx.z;
  const float* Wm = (mat == 0) ? Wq : ((mat == 1) ? Wk : Wv);
  const int k0 = blockIdx.y * 64, n0 = blockIdx.x * 64;
  const int t = threadIdx.x;
  const int c = t & 63, r0 = t >> 6;
  #pragma unroll
  for (int i = 0; i < 16; i++) {
    const int r = i * 4 + r0;
    tile[r][c] = Wm[(size_t)(k0 + r) * HID + n0 + c];
  }
  __syncthreads();
  ushort* Wt = Wtb + (size_t)mat * HID * HID;
  #pragma unroll
  for (int i = 0; i < 16; i++) {
    const int r = i * 4 + r0;
    Wt[(size_t)(n0 + r) * HID + k0 + c] = f2bf(tile[c][r]);
  }
}

// -------------------------------------------------------------- projection GEMM
// C = Xb @ W  (M=16384, N=512, K=512), 3 mats. 128x128 tile, BK=64, 4 waves,
// each wave 64x64 (4x4 of 16x16x32). global_load_lds(16B) staging with XOR
// slot-swizzle (applied to BOTH global source and LDS read -> LDS dest linear,
// ds_read_b128 conflict-free). XCD-locality: xcd = bid&7 owns a contiguous
// 2048-row X slice (2MB) + all W (1.5MB) -> fits the XCD's 4MB L2.
// mat 0/1 -> Qb/Kb row-major [B*S][H]; mat 2 -> Vtb BLOCKED [b][s/32][h][32].
__global__ void __launch_bounds__(256) proj_kernel(
    const ushort* __restrict__ Xb, const ushort* __restrict__ Wtb,
    ushort* __restrict__ Qb, ushort* __restrict__ Kb, ushort* __restrict__ Vtb) {
  __shared__ __align__(16) ushort lsA[128 * 64];
  __shared__ __align__(16) ushort lsB[128 * 64];
  const int bid  = blockIdx.x;
  const int xcd  = bid & 7;
  const int idx  = bid >> 3;            // 0..191 within XCD
  const int rsub = idx / 12;            // 0..15  row-chunk within XCD slice
  const int cm   = idx - rsub * 12;     // 0..11  mat*4 + column-tile
  const int mat  = cm >> 2;
  const int C0   = (cm & 3) * 128;
  const int R0   = (xcd * 16 + rsub) * 128;
  const int tid = threadIdx.x;
  const int w = tid >> 6, l = tid & 63;
  const int hl = l >> 4, l15 = l & 15;
  const int wr = w >> 1, wc = w & 1;
  const ushort* Wm = Wtb + (size_t)mat * HID * HID;

  const int srow = l >> 3;
  const int scol = ((l & 7) ^ srow) * 8;

  f32x4 acc[4][4] = {};

  for (int k0 = 0; k0 < HID; k0 += 64) {
    #pragma unroll
    for (int j = 0; j < 4; j++) {
      const int i = w * 4 + j;
      const int r = i * 8 + srow;
      gld_lds16(Xb + (size_t)(R0 + r) * HID + k0 + scol, lsA + i * 512);
      gld_lds16(Wm + (size_t)(C0 + r) * HID + k0 + scol, lsB + i * 512);
    }
    __syncthreads();
    #pragma unroll
    for (int kf = 0; kf < 2; kf++) {
      bf16x8 af[4], bfr[4];
      #pragma unroll
      for (int mi = 0; mi < 4; mi++) {
        const int r  = wr * 64 + mi * 16 + l15;
        const int sl = ((kf * 4 + hl) ^ (r & 7)) * 8;
        af[mi] = *(const bf16x8*)(lsA + r * 64 + sl);
      }
      #pragma unroll
      for (int nj = 0; nj < 4; nj++) {
        const int r  = wc * 64 + nj * 16 + l15;
        const int sl = ((kf * 4 + hl) ^ (r & 7)) * 8;
        bfr[nj] = *(const bf16x8*)(lsB + r * 64 + sl);
      }
      #pragma unroll
      for (int mi = 0; mi < 4; mi++)
        #pragma unroll
        for (int nj = 0; nj < 4; nj++)
          acc[mi][nj] = __builtin_amdgcn_mfma_f32_16x16x32_bf16(
              af[mi], bfr[nj], acc[mi][nj], 0, 0, 0);
    }
    __syncthreads();
  }

  if (mat < 2) {
    ushort* Op = (mat == 0) ? Qb : Kb;
    #pragma unroll
    for (int mi = 0; mi < 4; mi++) {
      const int row = R0 + wr * 64 + mi * 16 + hl * 4;
      #pragma unroll
      for (int nj = 0; nj < 4; nj++) {
        const int col = C0 + wc * 64 + nj * 16 + l15;
        #pragma unroll
        for (int i = 0; i < 4; i++)
          Op[(size_t)(row + i) * HID + col] = f2bf(acc[mi][nj][i]);
      }
    }
  } else {
    // V blocked: Vtb[b][s>>5][h][s&31]; acc's 4 elems are consecutive s
    const int b  = R0 >> 11;
    const int sb = (R0 & 2047) + wr * 64;        // multiple of 64
    ushort* Vt = Vtb + (size_t)b * (64 * 512 * 32);
    #pragma unroll
    for (int mi = 0; mi < 4; mi++) {
      const int s = sb + mi * 16 + hl * 4;
      const size_t blk = (size_t)(s >> 5) * (512 * 32) + (s & 31);
      #pragma unroll
      for (int nj = 0; nj < 4; nj++) {
        const int col = C0 + wc * 64 + nj * 16 + l15;
        ushort4 pk;
        pk.x = f2bf(acc[mi][nj][0]); pk.y = f2bf(acc[mi][nj][1]);
        pk.z = f2bf(acc[mi][nj][2]); pk.w = f2bf(acc[mi][nj][3]);
        *(ushort4*)(Vt + blk + (size_t)col * 32) = pk;
      }
    }
  }
}

// ------------------------------------------------------------- fused retention
// Block = 64 q-rows, 4 waves, each wave 16 q-rows x full H=512.
// Software-pipelined: per iteration one barrier-free region holds
//   STAGE_K(t+1) (DMA, dbuf) || PV(t-1) (global V, indep chains) || QK(t),
// then swish(t) -> P[t&1] (wave-private dbuf), then ONE barrier
// (Kbuf WAR protection + stage drain; covered by the whole body).
// K swizzle rule 21: pre-swizzled global source, linear LDS dest,
// swizzled ds_read. V read straight from blocked Vtb (contiguous 1KB/frag,
// L2-resident; per-batch K+V = 4MB = pinned XCD's L2, b = bid&7).
__global__ void __launch_bounds__(256, 1) attn_kernel(
    const ushort* __restrict__ Qb, const ushort* __restrict__ Kb,
    const ushort* __restrict__ Vtb, float* __restrict__ Out) {
  __shared__ __align__(16) ushort Kbuf[2][32 * 512];   // 64KB dbuf
  __shared__ __align__(16) ushort Pbuf[2][4][16 * 40]; // 10KB dbuf, per-wave
  const int b = blockIdx.x & 7, q0 = (blockIdx.x >> 3) * 64;
  const int tid = threadIdx.x;
  const int w = tid >> 6, l = tid & 63;
  const int hl = l >> 4, l15 = l & 15;

  const ushort* Qp = Qb + ((size_t)b * S_LEN + q0 + w * 16) * HID;
  const ushort* Kp = Kb + (size_t)b * S_LEN * HID;
  const ushort* Vt = Vtb + (size_t)b * (64 * 512 * 32);

  // hoist this wave's Q rows (16 x 512) into registers: 64 VGPR
  bf16x8 qf[16];
  #pragma unroll
  for (int kf = 0; kf < 16; kf++)
    qf[kf] = *(const bf16x8*)(Qp + (size_t)l15 * HID + kf * 32 + hl * 8);

  f32x4 accO[32] = {};   // 16 rows x 512 cols fp32
  const int t_lo = (q0 - BAND) < 0 ? 0 : ((q0 - BAND) >> 5);
  int t_hi = ((q0 + 63 + BAND) >> 5) + 1;
  if (t_hi > S_LEN / 32) t_hi = S_LEN / 32;

  const float qrow = (float)(q0 + w * 16 + l15);

  // K staging: each wave stages 8 rows (1KB each, 1 instr = 64 lanes x 16B).
  // LDS[r][slot s] = G[r][s ^ (r&7)] -> read slot j at (j ^ (r&7)).
  #define STAGE_K(T, BUF)                                                   \
    {                                                                       \
      const ushort* Ks = Kp + (size_t)(T) * 32 * HID;                       \
      _Pragma("unroll")                                                     \
      for (int j = 0; j < 8; j++) {                                         \
        const int r = w * 8 + j;                                            \
        gld_lds16(Ks + (size_t)r * HID + ((l ^ (r & 7)) * 8),               \
                  (BUF) + r * HID);                                         \
      }                                                                     \
    }

  // QK^T (swapped): ST[kv 32][q 16], K A-frags from swizzled LDS
  #define QK_TILE(BUF, ST)                                                  \
    _Pragma("unroll")                                                       \
    for (int kf = 0; kf < 16; kf++) {                                       \
      _Pragma("unroll")                                                     \
      for (int mf = 0; mf < 2; mf++) {                                      \
        const int r = mf * 16 + l15;                                        \
        const int j = kf * 4 + hl;                                          \
        bf16x8 kfr = *(const bf16x8*)((BUF) + r * HID + ((j ^ (r & 7)) * 8)); \
        ST[mf] = __builtin_amdgcn_mfma_f32_16x16x32_bf16(kfr, qf[kf], ST[mf], 0, 0, 0); \
      }                                                                     \
    }

  // decay + swish on ST, pack P[q16][kv32] into wave-private LDS buffer
  #define SWISH_P(T, ST, PW)                                                \
    _Pragma("unroll")                                                       \
    for (int mf = 0; mf < 2; mf++) {                                        \
      ushort4 pk;                                                           \
      _Pragma("unroll")                                                     \
      for (int i = 0; i < 4; i++) {                                         \
        const float kvf = (float)((T) * 32 + mf * 16 + hl * 4 + i);         \
        const float ad = fabsf(kvf - qrow);                                 \
        const float s = ST[mf][i] * exp2f(GAMMA_L2 * ad);                   \
        const float p = s * __builtin_amdgcn_rcpf(1.0f + exp2f(-LOG2E * s));\
        ((ushort*)&pk)[i] = f2bf(p);                                        \
      }                                                                     \
      *(ushort4*)((PW) + l15 * 40 + mf * 16 + hl * 4) = pk;                 \
    }

  // PV: O[q][h] += P[q][kv32] * V[kv32][h]; V blocked -> contiguous 1KB frag
  #define PV_TILE(T, PW)                                                    \
    {                                                                       \
      bf16x8 pf = *(const bf16x8*)((PW) + l15 * 40 + hl * 8);               \
      const ushort* Vbase = Vt + (size_t)(T) * (512 * 32) + hl * 8;         \
      _Pragma("unroll")                                                     \
      for (int nf = 0; nf < 32; nf++) {                                     \
        bf16x8 vf = *(const bf16x8*)(Vbase + (nf * 16 + l15) * 32);         \
        accO[nf] = __builtin_amdgcn_mfma_f32_16x16x32_bf16(pf, vf, accO[nf], 0, 0, 0); \
      }                                                                     \
    }

  STAGE_K(t_lo, Kbuf[t_lo & 1]);
  __syncthreads();                       // drain prologue stage

  {                                      // prologue iter t_lo (no PV yet)
    const int t = t_lo;
    if (t + 1 < t_hi) STAGE_K(t + 1, Kbuf[(t + 1) & 1]);
    f32x4 st[2] = {};
    QK_TILE(Kbuf[t & 1], st);
    SWISH_P(t, st, Pbuf[t & 1][w]);
    __syncthreads();
  }

  for (int t = t_lo + 1; t < t_hi; ++t) {
    if (t + 1 < t_hi) STAGE_K(t + 1, Kbuf[(t + 1) & 1]);
    PV_TILE(t - 1, Pbuf[(t - 1) & 1][w]);    // independent of QK(t) below
    f32x4 st[2] = {};
    QK_TILE(Kbuf[t & 1], st);
    SWISH_P(t, st, Pbuf[t & 1][w]);
    __syncthreads();                     // Kbuf WAR + stage drain (one/iter)
  }

  PV_TILE(t_hi - 1, Pbuf[(t_hi - 1) & 1][w]);  // epilogue PV

  // --- epilogue: each wave owns its 16 rows -> direct store
  float* Ob = Out + ((size_t)b * S_LEN + q0 + w * 16) * HID;
  #pragma unroll
  for (int nf = 0; nf < 32; nf++)
    #pragma unroll
    for (int i = 0; i < 4; i++)
      Ob[(size_t)(hl * 4 + i) * HID + nf * 16 + l15] = accO[nf][i];
}

// ---------------------------------------------------------------------- launch
extern "C" void kernel_launch(void* const* d_in, const int* in_sizes, int n_in,
                              void* d_out, int out_size, void* d_ws, size_t ws_size,
                              hipStream_t stream) {
  const float* X  = (const float*)d_in[0];
  const float* Wq = (const float*)d_in[1];
  const float* Wk = (const float*)d_in[2];
  const float* Wv = (const float*)d_in[3];
  float* Out = (float*)d_out;

  char* ws = (char*)d_ws;
  ushort* Xb  = (ushort*)(ws);                      // 16 MiB  bf16 X
  ushort* Wtb = (ushort*)(ws + 16777216);           // 1.5 MiB bf16 W^T x3
  ushort* Qb  = (ushort*)(ws + 18350080);           // 16 MiB
  ushort* Kb  = (ushort*)(ws + 35127296);           // 16 MiB
  ushort* Vtb = (ushort*)(ws + 51904512);           // 16 MiB (blocked V)

  cvt_x_kernel<<<2048, 256, 0, stream>>>(X, Xb);
  cvt_w_kernel<<<dim3(8, 8, 3), 256, 0, stream>>>(Wq, Wk, Wv, Wtb);
  proj_kernel<<<1536, 256, 0, stream>>>(Xb, Wtb, Qb, Kb, Vtb);
  attn_kernel<<<256, 256, 0, stream>>>(Qb, Kb, Vtb, Out);
}

// Round 5
// 229.766 us; speedup vs baseline: 1.0014x; 1.0014x over previous
//
#include <hip/hip_runtime.h>

// SimpleRetention on MI355X (gfx950), bf16 MFMA path.
// ret = (S * sigmoid(S)) @ V,  S = (Q K^T) * gamma^|n-m|
// B=8, S=2048, H=512, gamma = 31/32. Decay band truncated at +-256..319
// (gamma^256 ~ 2.9e-4 -> contribution << 2%-of-absmax threshold).
//
// v4: attn rebuilt for TLP. Round-3/4 lesson: grid was 256 blocks = 1
// wave/SIMD -> all latency exposed (Occupancy 10%, nothing busy). Now:
// fragment-linear global layouts (Q/K: [r/16][h/8][16][8]; V per batch:
// [h/16][s/8][16][8]) make every MFMA operand a contiguous-1KB-per-wave
// global load -> no K LDS staging, no mid-loop barriers; QBLK=16 with
// 2 waves kv-splitting even/odd tiles -> 1024 blocks = 4/CU = 2 waves/SIMD.

typedef short  bf16x8 __attribute__((ext_vector_type(8)));
typedef float  f32x4  __attribute__((ext_vector_type(4)));

constexpr int S_LEN = 2048;
constexpr int HID   = 512;
constexpr int BAND  = 256;

#define GAMMA_L2 (-0.045803689613125f)   /* log2(31/32) */
#define LOG2E    (1.4426950408889634f)

__device__ __forceinline__ ushort f2bf(float f) {
  union { float f; unsigned u; } v; v.f = f;
  unsigned u = v.u;
  u += 0x7FFFu + ((u >> 16) & 1u);      // RNE, matches v_cvt
  return (ushort)(u >> 16);
}

__device__ __forceinline__ void gld_lds16(const ushort* g, ushort* l) {
  __builtin_amdgcn_global_load_lds(
      (const __attribute__((address_space(1))) void*)g,
      (__attribute__((address_space(3))) void*)l, 16, 0, 0);
}

// ---------------------------------------------------------------- cvt X -> bf16
__global__ void cvt_x_kernel(const float* __restrict__ X, ushort* __restrict__ Xb) {
  const int n4 = (8 * S_LEN * HID) / 4;
  int i = blockIdx.x * blockDim.x + threadIdx.x;
  const int stride = gridDim.x * blockDim.x;
  for (; i < n4; i += stride) {
    float4 v = ((const float4*)X)[i];
    ushort4 o;
    o.x = f2bf(v.x); o.y = f2bf(v.y); o.z = f2bf(v.z); o.w = f2bf(v.w);
    ((ushort4*)Xb)[i] = o;
  }
}

// ------------------------------------------------ cvt + transpose W -> Wt bf16
// Wtb[mat][n][k] = W_mat[k][n]  (so GEMM B-fragments are contiguous along K)
__global__ void cvt_w_kernel(const float* __restrict__ Wq, const float* __restrict__ Wk,
                             const float* __restrict__ Wv, ushort* __restrict__ Wtb) {
  __shared__ float tile[64][65];
  const int mat = blockIdx.z;
  const float* Wm = (mat == 0) ? Wq : ((mat == 1) ? Wk : Wv);
  const int k0 = blockIdx.y * 64, n0 = blockIdx.x * 64;
  const int t = threadIdx.x;
  const int c = t & 63, r0 = t >> 6;
  #pragma unroll
  for (int i = 0; i < 16; i++) {
    const int r = i * 4 + r0;
    tile[r][c] = Wm[(size_t)(k0 + r) * HID + n0 + c];
  }
  __syncthreads();
  ushort* Wt = Wtb + (size_t)mat * HID * HID;
  #pragma unroll
  for (int i = 0; i < 16; i++) {
    const int r = i * 4 + r0;
    Wt[(size_t)(n0 + r) * HID + k0 + c] = f2bf(tile[c][r]);
  }
}

// -------------------------------------------------------------- projection GEMM
// C = Xb @ W  (M=16384, N=512, K=512), 3 mats. 128x128 tile, BK=64, 4 waves,
// each wave 64x64 (4x4 of 16x16x32). global_load_lds(16B) staging with XOR
// slot-swizzle (both-sides, rule 21). XCD-locality: xcd = bid&7 owns a
// contiguous 2048-row X slice (2MB) + all W (1.5MB) -> fits the XCD's 4MB L2.
// Outputs in FRAGMENT-LINEAR layouts for the attn kernel:
//   mat 0/1 -> Q2/K2: addr(r,h) = (r>>4)*8192 + (h>>3)*128 + (r&15)*8 + (h&7)
//   mat 2   -> V2 per batch b=r>>11, sb=r&2047:
//              b*1048576 + (h>>4)*32768 + (sb>>3)*128 + (h&15)*8 + (sb&7)
__global__ void __launch_bounds__(256) proj_kernel(
    const ushort* __restrict__ Xb, const ushort* __restrict__ Wtb,
    ushort* __restrict__ Qb, ushort* __restrict__ Kb, ushort* __restrict__ Vtb) {
  __shared__ __align__(16) ushort lsA[128 * 64];
  __shared__ __align__(16) ushort lsB[128 * 64];
  const int bid  = blockIdx.x;
  const int xcd  = bid & 7;
  const int idx  = bid >> 3;            // 0..191 within XCD
  const int rsub = idx / 12;            // 0..15  row-chunk within XCD slice
  const int cm   = idx - rsub * 12;     // 0..11  mat*4 + column-tile
  const int mat  = cm >> 2;
  const int C0   = (cm & 3) * 128;
  const int R0   = (xcd * 16 + rsub) * 128;
  const int tid = threadIdx.x;
  const int w = tid >> 6, l = tid & 63;
  const int hl = l >> 4, l15 = l & 15;
  const int wr = w >> 1, wc = w & 1;
  const ushort* Wm = Wtb + (size_t)mat * HID * HID;

  const int srow = l >> 3;
  const int scol = ((l & 7) ^ srow) * 8;

  f32x4 acc[4][4] = {};

  for (int k0 = 0; k0 < HID; k0 += 64) {
    #pragma unroll
    for (int j = 0; j < 4; j++) {
      const int i = w * 4 + j;
      const int r = i * 8 + srow;
      gld_lds16(Xb + (size_t)(R0 + r) * HID + k0 + scol, lsA + i * 512);
      gld_lds16(Wm + (size_t)(C0 + r) * HID + k0 + scol, lsB + i * 512);
    }
    __syncthreads();
    #pragma unroll
    for (int kf = 0; kf < 2; kf++) {
      bf16x8 af[4], bfr[4];
      #pragma unroll
      for (int mi = 0; mi < 4; mi++) {
        const int r  = wr * 64 + mi * 16 + l15;
        const int sl = ((kf * 4 + hl) ^ (r & 7)) * 8;
        af[mi] = *(const bf16x8*)(lsA + r * 64 + sl);
      }
      #pragma unroll
      for (int nj = 0; nj < 4; nj++) {
        const int r  = wc * 64 + nj * 16 + l15;
        const int sl = ((kf * 4 + hl) ^ (r & 7)) * 8;
        bfr[nj] = *(const bf16x8*)(lsB + r * 64 + sl);
      }
      #pragma unroll
      for (int mi = 0; mi < 4; mi++)
        #pragma unroll
        for (int nj = 0; nj < 4; nj++)
          acc[mi][nj] = __builtin_amdgcn_mfma_f32_16x16x32_bf16(
              af[mi], bfr[nj], acc[mi][nj], 0, 0, 0);
    }
    __syncthreads();
  }

  if (mat < 2) {
    ushort* Op = (mat == 0) ? Qb : Kb;
    #pragma unroll
    for (int mi = 0; mi < 4; mi++) {
      const int r16 = R0 + wr * 64 + mi * 16;          // multiple of 16
      const size_t sb = ((size_t)r16 >> 4) * 8192;
      #pragma unroll
      for (int nj = 0; nj < 4; nj++) {
        const int h = C0 + wc * 64 + nj * 16 + l15;
        const size_t ha = sb + (size_t)(h >> 3) * 128 + (h & 7);
        #pragma unroll
        for (int i = 0; i < 4; i++)
          Op[ha + (hl * 4 + i) * 8] = f2bf(acc[mi][nj][i]);
      }
    }
  } else {
    // V2: per batch [h/16][s/8][16][8]; i runs along s&7 -> ushort4 store
    const int b = R0 >> 11;
    ushort* Vt = Vtb + (size_t)b * 1048576;
    #pragma unroll
    for (int mi = 0; mi < 4; mi++) {
      const int sb16 = (R0 & 2047) + wr * 64 + mi * 16;  // multiple of 16
      const size_t sa = (size_t)((sb16 >> 3) + (hl >> 1)) * 128 + (hl & 1) * 4;
      #pragma unroll
      for (int nj = 0; nj < 4; nj++) {
        const int hv = (C0 + wc * 64) / 16 + nj;
        ushort4 pk;
        pk.x = f2bf(acc[mi][nj][0]); pk.y = f2bf(acc[mi][nj][1]);
        pk.z = f2bf(acc[mi][nj][2]); pk.w = f2bf(acc[mi][nj][3]);
        *(ushort4*)(Vt + (size_t)hv * 32768 + sa + l15 * 8) = pk;
      }
    }
  }
}

// ------------------------------------------------------------- fused retention
// Block = 16 q-rows, 2 waves kv-splitting even/odd 32-row tiles. All MFMA
// operands loaded DIRECTLY from global in fragment-linear layouts (each wave
// load = contiguous 1KB, L2-resident; b = bid&7 pins batch->XCD so per-batch
// K2+V2 = 4MB fills its L2). No barriers in the loop; P transposed through
// wave-private LDS (lgkmcnt-ordered). End: 2-chunk LDS reduction of the two
// waves' partial accO, wave 0 stores. 1024 blocks = 4/CU -> 2 waves/SIMD.
__global__ void __launch_bounds__(128, 2) attn_kernel(
    const ushort* __restrict__ Q2, const ushort* __restrict__ K2,
    const ushort* __restrict__ V2, float* __restrict__ Out) {
  __shared__ __align__(16) ushort Pbuf[2][16 * 40];
  __shared__ __align__(16) float red[16 * 320];      // 20KB, conflict-padded
  const int b = blockIdx.x & 7, q0 = (blockIdx.x >> 3) * 16;
  const int tid = threadIdx.x;
  const int w = tid >> 6, l = tid & 63;
  const int hl = l >> 4, l15 = l & 15;

  // Q B-frags: 16 x contiguous-1KB wave loads, hoisted to registers (64 VGPR)
  const ushort* Qp = Q2 + ((size_t)(b * 128 + (q0 >> 4))) * 8192 + hl * 128 + l15 * 8;
  bf16x8 qf[16];
  #pragma unroll
  for (int kf = 0; kf < 16; kf++)
    qf[kf] = *(const bf16x8*)(Qp + kf * 512);

  f32x4 accO[32] = {};   // 16 rows x 512 cols fp32 (partial: this wave's tiles)
  const int t_lo = (q0 - BAND) < 0 ? 0 : ((q0 - BAND) >> 5);
  int t_hi = ((q0 + 15 + BAND) >> 5) + 1;
  if (t_hi > S_LEN / 32) t_hi = S_LEN / 32;

  ushort* Pw = Pbuf[w];
  const float qrow = (float)(q0 + l15);
  const ushort* Vb = V2 + (size_t)b * 1048576 + hl * 128 + l15 * 8;

  for (int t = t_lo + w; t < t_hi; t += 2) {
    // --- QK^T (swapped): ST[kv 32][q 16]; K A-frags direct from global
    const ushort* Kt = K2 + ((size_t)(b * 128 + t * 2)) * 8192 + hl * 128 + l15 * 8;
    f32x4 st[2] = {};
    #pragma unroll
    for (int kq = 0; kq < 4; kq++) {
      bf16x8 kr0[4], kr1[4];
      #pragma unroll
      for (int j = 0; j < 4; j++) {
        kr0[j] = *(const bf16x8*)(Kt + (kq * 4 + j) * 512);
        kr1[j] = *(const bf16x8*)(Kt + 8192 + (kq * 4 + j) * 512);
      }
      #pragma unroll
      for (int j = 0; j < 4; j++) {
        st[0] = __builtin_amdgcn_mfma_f32_16x16x32_bf16(kr0[j], qf[kq * 4 + j], st[0], 0, 0, 0);
        st[1] = __builtin_amdgcn_mfma_f32_16x16x32_bf16(kr1[j], qf[kq * 4 + j], st[1], 0, 0, 0);
      }
    }
    // --- decay + swish, pack P[q16][kv32] into wave-private LDS
    #pragma unroll
    for (int mf = 0; mf < 2; mf++) {
      ushort4 pk;
      #pragma unroll
      for (int i = 0; i < 4; i++) {
        const float kvf = (float)(t * 32 + mf * 16 + hl * 4 + i);
        const float ad = fabsf(kvf - qrow);
        const float s = st[mf][i] * exp2f(GAMMA_L2 * ad);
        const float p = s * __builtin_amdgcn_rcpf(1.0f + exp2f(-LOG2E * s));
        ((ushort*)&pk)[i] = f2bf(p);
      }
      *(ushort4*)(Pw + l15 * 40 + mf * 16 + hl * 4) = pk;
    }
    // --- PV: O[q][h] += P * V[kv32][h]; V B-frags direct from global
    bf16x8 pf = *(const bf16x8*)(Pw + l15 * 40 + hl * 8);
    const ushort* Vt = Vb + (size_t)t * 512;
    #pragma unroll
    for (int g = 0; g < 8; g++) {
      bf16x8 vr[4];
      #pragma unroll
      for (int j = 0; j < 4; j++)
        vr[j] = *(const bf16x8*)(Vt + (size_t)(g * 4 + j) * 32768);
      #pragma unroll
      for (int j = 0; j < 4; j++)
        accO[g * 4 + j] = __builtin_amdgcn_mfma_f32_16x16x32_bf16(pf, vr[j], accO[g * 4 + j], 0, 0, 0);
    }
  }

  // --- pairwise reduction (2 chunks of 16 f32x4/lane through 20KB LDS)
  #pragma unroll
  for (int ch = 0; ch < 2; ch++) {
    if (w == 1) {
      #pragma unroll
      for (int k = 0; k < 16; k++)
        *(f32x4*)(red + k * 320 + l15 * 20 + hl * 4) = accO[ch * 16 + k];
    }
    __syncthreads();
    if (w == 0) {
      #pragma unroll
      for (int k = 0; k < 16; k++)
        accO[ch * 16 + k] += *(const f32x4*)(red + k * 320 + l15 * 20 + hl * 4);
    }
    __syncthreads();
  }
  if (w == 0) {
    float* Ob = Out + ((size_t)b * S_LEN + q0) * HID;
    #pragma unroll
    for (int nf = 0; nf < 32; nf++)
      #pragma unroll
      for (int i = 0; i < 4; i++)
        Ob[(size_t)(hl * 4 + i) * HID + nf * 16 + l15] = accO[nf][i];
  }
}

// ---------------------------------------------------------------------- launch
extern "C" void kernel_launch(void* const* d_in, const int* in_sizes, int n_in,
                              void* d_out, int out_size, void* d_ws, size_t ws_size,
                              hipStream_t stream) {
  const float* X  = (const float*)d_in[0];
  const float* Wq = (const float*)d_in[1];
  const float* Wk = (const float*)d_in[2];
  const float* Wv = (const float*)d_in[3];
  float* Out = (float*)d_out;

  char* ws = (char*)d_ws;
  ushort* Xb  = (ushort*)(ws);                      // 16 MiB  bf16 X
  ushort* Wtb = (ushort*)(ws + 16777216);           // 1.5 MiB bf16 W^T x3
  ushort* Qb  = (ushort*)(ws + 18350080);           // 16 MiB (frag-linear Q2)
  ushort* Kb  = (ushort*)(ws + 35127296);           // 16 MiB (frag-linear K2)
  ushort* Vtb = (ushort*)(ws + 51904512);           // 16 MiB (frag-linear V2)

  cvt_x_kernel<<<2048, 256, 0, stream>>>(X, Xb);
  cvt_w_kernel<<<dim3(8, 8, 3), 256, 0, stream>>>(Wq, Wk, Wv, Wtb);
  proj_kernel<<<1536, 256, 0, stream>>>(Xb, Wtb, Qb, Kb, Vtb);
  attn_kernel<<<1024, 128, 0, stream>>>(Qb, Kb, Vtb, Out);
}

// Round 6
// 181.442 us; speedup vs baseline: 1.2681x; 1.2663x over previous
//
#include <hip/hip_runtime.h>

// SimpleRetention on MI355X (gfx950), bf16 MFMA path.
// ret = (S * sigmoid(S)) @ V,  S = (Q K^T) * gamma^|n-m|
// B=8, S=2048, H=512, gamma = 31/32. Decay band truncated at +-256..319.
//
// v5: attn occupancy fix. Round-5 evidence: accO[32] (128 unified-file regs)
// capped residency at 2 waves/SIMD (Occupancy 13%) -> all L2 latency exposed.
// Now: 4-wave blocks, kv-split QK + h-split PV through a shared LDS P tile:
// accO[8] (32 regs), Q in LDS (16KB) instead of 64 VGPRs -> ~110 VGPR ->
// 4 waves/SIMD; grid 1024x4 waves = full 16-waves/CU residency, 1 barrier
// per 64-kv tile. All operands from L2-resident fragment-linear layouts.

typedef short  bf16x8 __attribute__((ext_vector_type(8)));
typedef float  f32x4  __attribute__((ext_vector_type(4)));

constexpr int S_LEN = 2048;
constexpr int HID   = 512;
constexpr int BAND  = 256;

#define GAMMA_L2 (-0.045803689613125f)   /* log2(31/32) */
#define LOG2E    (1.4426950408889634f)

__device__ __forceinline__ ushort f2bf(float f) {
  union { float f; unsigned u; } v; v.f = f;
  unsigned u = v.u;
  u += 0x7FFFu + ((u >> 16) & 1u);      // RNE, matches v_cvt
  return (ushort)(u >> 16);
}

__device__ __forceinline__ void gld_lds16(const ushort* g, ushort* l) {
  __builtin_amdgcn_global_load_lds(
      (const __attribute__((address_space(1))) void*)g,
      (__attribute__((address_space(3))) void*)l, 16, 0, 0);
}

// ---------------------------------------------------------------- cvt X -> bf16
__global__ void cvt_x_kernel(const float* __restrict__ X, ushort* __restrict__ Xb) {
  const int n4 = (8 * S_LEN * HID) / 4;
  int i = blockIdx.x * blockDim.x + threadIdx.x;
  const int stride = gridDim.x * blockDim.x;
  for (; i < n4; i += stride) {
    float4 v = ((const float4*)X)[i];
    ushort4 o;
    o.x = f2bf(v.x); o.y = f2bf(v.y); o.z = f2bf(v.z); o.w = f2bf(v.w);
    ((ushort4*)Xb)[i] = o;
  }
}

// ------------------------------------------------ cvt + transpose W -> Wt bf16
__global__ void cvt_w_kernel(const float* __restrict__ Wq, const float* __restrict__ Wk,
                             const float* __restrict__ Wv, ushort* __restrict__ Wtb) {
  __shared__ float tile[64][65];
  const int mat = blockIdx.z;
  const float* Wm = (mat == 0) ? Wq : ((mat == 1) ? Wk : Wv);
  const int k0 = blockIdx.y * 64, n0 = blockIdx.x * 64;
  const int t = threadIdx.x;
  const int c = t & 63, r0 = t >> 6;
  #pragma unroll
  for (int i = 0; i < 16; i++) {
    const int r = i * 4 + r0;
    tile[r][c] = Wm[(size_t)(k0 + r) * HID + n0 + c];
  }
  __syncthreads();
  ushort* Wt = Wtb + (size_t)mat * HID * HID;
  #pragma unroll
  for (int i = 0; i < 16; i++) {
    const int r = i * 4 + r0;
    Wt[(size_t)(n0 + r) * HID + k0 + c] = f2bf(tile[c][r]);
  }
}

// -------------------------------------------------------------- projection GEMM
// (unchanged from v4 — verified passing). Outputs fragment-linear:
//   Q2/K2: addr(r,h) = (r>>4)*8192 + (h>>3)*128 + (r&15)*8 + (h&7)
//   V2 per batch: b*1048576 + (h>>4)*32768 + (s>>3)*128 + (h&15)*8 + (s&7)
__global__ void __launch_bounds__(256) proj_kernel(
    const ushort* __restrict__ Xb, const ushort* __restrict__ Wtb,
    ushort* __restrict__ Qb, ushort* __restrict__ Kb, ushort* __restrict__ Vtb) {
  __shared__ __align__(16) ushort lsA[128 * 64];
  __shared__ __align__(16) ushort lsB[128 * 64];
  const int bid  = blockIdx.x;
  const int xcd  = bid & 7;
  const int idx  = bid >> 3;
  const int rsub = idx / 12;
  const int cm   = idx - rsub * 12;
  const int mat  = cm >> 2;
  const int C0   = (cm & 3) * 128;
  const int R0   = (xcd * 16 + rsub) * 128;
  const int tid = threadIdx.x;
  const int w = tid >> 6, l = tid & 63;
  const int hl = l >> 4, l15 = l & 15;
  const int wr = w >> 1, wc = w & 1;
  const ushort* Wm = Wtb + (size_t)mat * HID * HID;

  const int srow = l >> 3;
  const int scol = ((l & 7) ^ srow) * 8;

  f32x4 acc[4][4] = {};

  for (int k0 = 0; k0 < HID; k0 += 64) {
    #pragma unroll
    for (int j = 0; j < 4; j++) {
      const int i = w * 4 + j;
      const int r = i * 8 + srow;
      gld_lds16(Xb + (size_t)(R0 + r) * HID + k0 + scol, lsA + i * 512);
      gld_lds16(Wm + (size_t)(C0 + r) * HID + k0 + scol, lsB + i * 512);
    }
    __syncthreads();
    #pragma unroll
    for (int kf = 0; kf < 2; kf++) {
      bf16x8 af[4], bfr[4];
      #pragma unroll
      for (int mi = 0; mi < 4; mi++) {
        const int r  = wr * 64 + mi * 16 + l15;
        const int sl = ((kf * 4 + hl) ^ (r & 7)) * 8;
        af[mi] = *(const bf16x8*)(lsA + r * 64 + sl);
      }
      #pragma unroll
      for (int nj = 0; nj < 4; nj++) {
        const int r  = wc * 64 + nj * 16 + l15;
        const int sl = ((kf * 4 + hl) ^ (r & 7)) * 8;
        bfr[nj] = *(const bf16x8*)(lsB + r * 64 + sl);
      }
      #pragma unroll
      for (int mi = 0; mi < 4; mi++)
        #pragma unroll
        for (int nj = 0; nj < 4; nj++)
          acc[mi][nj] = __builtin_amdgcn_mfma_f32_16x16x32_bf16(
              af[mi], bfr[nj], acc[mi][nj], 0, 0, 0);
    }
    __syncthreads();
  }

  if (mat < 2) {
    ushort* Op = (mat == 0) ? Qb : Kb;
    #pragma unroll
    for (int mi = 0; mi < 4; mi++) {
      const int r16 = R0 + wr * 64 + mi * 16;
      const size_t sb = ((size_t)r16 >> 4) * 8192;
      #pragma unroll
      for (int nj = 0; nj < 4; nj++) {
        const int h = C0 + wc * 64 + nj * 16 + l15;
        const size_t ha = sb + (size_t)(h >> 3) * 128 + (h & 7);
        #pragma unroll
        for (int i = 0; i < 4; i++)
          Op[ha + (hl * 4 + i) * 8] = f2bf(acc[mi][nj][i]);
      }
    }
  } else {
    const int b = R0 >> 11;
    ushort* Vt = Vtb + (size_t)b * 1048576;
    #pragma unroll
    for (int mi = 0; mi < 4; mi++) {
      const int sb16 = (R0 & 2047) + wr * 64 + mi * 16;
      const size_t sa = (size_t)((sb16 >> 3) + (hl >> 1)) * 128 + (hl & 1) * 4;
      #pragma unroll
      for (int nj = 0; nj < 4; nj++) {
        const int hv = (C0 + wc * 64) / 16 + nj;
        ushort4 pk;
        pk.x = f2bf(acc[mi][nj][0]); pk.y = f2bf(acc[mi][nj][1]);
        pk.z = f2bf(acc[mi][nj][2]); pk.w = f2bf(acc[mi][nj][3]);
        *(ushort4*)(Vt + (size_t)hv * 32768 + sa + l15 * 8) = pk;
      }
    }
  }
}

// ------------------------------------------------------------- fused retention
// Block = 16 q-rows, 4 waves, KVBLK=64. Wave w: QK for kv rows [16w,16w+16)
// (16 K-loads from frag-linear K2 + 16 MFMA, Q B-frags from LDS), swish,
// write P quarter to shared LDS; barrier; PV for h-quarter [128w,128w+128)
// (full P via 2 conflict-free ds_read_b128, 16 V-loads, 16 MFMA -> accO[8]).
// 1024 blocks x 4 waves = 4096 waves = full residency at 4 waves/SIMD.
// b = bid&7 pins batch -> XCD (per-batch K2+V2 = 4MB = its L2).
__global__ void __launch_bounds__(256, 4) attn_kernel(
    const ushort* __restrict__ Q2, const ushort* __restrict__ K2,
    const ushort* __restrict__ V2, float* __restrict__ Out) {
  __shared__ __align__(16) ushort Qlds[16 * 512];     // 16KB, = Q2 block copy
  __shared__ __align__(16) ushort Pb[2][16 * 72];     // 4.5KB dbuf, 144B rows
  const int b = blockIdx.x & 7, q0 = (blockIdx.x >> 3) * 16;
  const int tid = threadIdx.x;
  const int w = tid >> 6, l = tid & 63;
  const int hl = l >> 4, l15 = l & 15;

  // stage Q tile (frag-linear 16KB block -> straight LDS copy)
  const ushort* Qg = Q2 + ((size_t)(b * 128 + (q0 >> 4))) * 8192;
  #pragma unroll
  for (int j = 0; j < 4; j++) {
    const int kf = w * 4 + j;
    gld_lds16(Qg + kf * 512 + l * 8, Qlds + kf * 512);
  }

  f32x4 accO[8] = {};    // 16 q-rows x 128 h-cols (this wave's H-quarter)
  const int t_lo = (q0 - BAND) < 0 ? 0 : ((q0 - BAND) >> 6);
  int t_hi = ((q0 + 15 + BAND) >> 6) + 1;
  if (t_hi > S_LEN / 64) t_hi = S_LEN / 64;

  const float qrow = (float)(q0 + l15);
  const int bK = b * 128;
  const ushort* Vb = V2 + (size_t)b * 1048576 + (size_t)w * 8 * 32768
                        + hl * 128 + l15 * 8;

  // QK quarter: S^T[kv 16w..16w+16][q 16]; K A-frags direct from L2
  #define QK_T(T, STV)                                                       \
    {                                                                        \
      const ushort* Kt = K2 + ((size_t)(bK + (T) * 4 + w)) * 8192 + l * 8;   \
      _Pragma("unroll")                                                      \
      for (int kf = 0; kf < 16; kf++) {                                      \
        bf16x8 kfr = *(const bf16x8*)(Kt + kf * 512);                        \
        bf16x8 qfr = *(const bf16x8*)(Qlds + kf * 512 + l * 8);              \
        STV = __builtin_amdgcn_mfma_f32_16x16x32_bf16(kfr, qfr, STV, 0, 0, 0); \
      }                                                                      \
    }

  // decay + swish on the quarter, pack into Pb[BUF] (rows=q l15, cols=kv)
  #define SWISH_P(T, STV, BUF)                                               \
    {                                                                        \
      ushort4 pk;                                                            \
      _Pragma("unroll")                                                      \
      for (int i = 0; i < 4; i++) {                                          \
        const float kvf = (float)((T) * 64 + w * 16 + hl * 4 + i);           \
        const float ad = fabsf(kvf - qrow);                                  \
        const float s = STV[i] * exp2f(GAMMA_L2 * ad);                       \
        const float p = s * __builtin_amdgcn_rcpf(1.0f + exp2f(-LOG2E * s)); \
        ((ushort*)&pk)[i] = f2bf(p);                                         \
      }                                                                      \
      *(ushort4*)(Pb[BUF] + l15 * 72 + w * 16 + hl * 4) = pk;                \
    }

  // PV: O[q][hq] += P[q][kv64] * V[kv64][hq]; P A-frags from LDS (conflict-
  // free: 144B row stride), V B-frags direct from L2 (contiguous 1KB/wave)
  #define PV_T(T, BUF)                                                       \
    {                                                                        \
      bf16x8 pa0 = *(const bf16x8*)(Pb[BUF] + l15 * 72 + hl * 8);            \
      bf16x8 pa1 = *(const bf16x8*)(Pb[BUF] + l15 * 72 + 32 + hl * 8);       \
      const ushort* Vt = Vb + (size_t)(T) * 1024;                            \
      _Pragma("unroll")                                                      \
      for (int nfi = 0; nfi < 8; nfi++) {                                    \
        bf16x8 v0 = *(const bf16x8*)(Vt + (size_t)nfi * 32768);              \
        bf16x8 v1 = *(const bf16x8*)(Vt + (size_t)nfi * 32768 + 512);        \
        accO[nfi] = __builtin_amdgcn_mfma_f32_16x16x32_bf16(pa0, v0, accO[nfi], 0, 0, 0); \
        accO[nfi] = __builtin_amdgcn_mfma_f32_16x16x32_bf16(pa1, v1, accO[nfi], 0, 0, 0); \
      }                                                                      \
    }

  __syncthreads();                       // Q staged (barrier drains vmcnt)

  {                                      // prologue: produce P(t_lo)
    f32x4 st = {};
    QK_T(t_lo, st);
    SWISH_P(t_lo, st, t_lo & 1);
  }
  __syncthreads();

  for (int t = t_lo; t < t_hi; ++t) {
    PV_T(t, t & 1);
    if (t + 1 < t_hi) {                  // produce P(t+1) in parallel w/ PV
      f32x4 st = {};
      QK_T(t + 1, st);
      SWISH_P(t + 1, st, (t + 1) & 1);
    }
    __syncthreads();                     // P(t+1) complete; P(t) buf freed
  }

  // epilogue: wave w stores its H-quarter
  float* Ob = Out + ((size_t)b * S_LEN + q0) * HID + w * 128;
  #pragma unroll
  for (int nfi = 0; nfi < 8; nfi++)
    #pragma unroll
    for (int i = 0; i < 4; i++)
      Ob[(size_t)(hl * 4 + i) * HID + nfi * 16 + l15] = accO[nfi][i];
}

// ---------------------------------------------------------------------- launch
extern "C" void kernel_launch(void* const* d_in, const int* in_sizes, int n_in,
                              void* d_out, int out_size, void* d_ws, size_t ws_size,
                              hipStream_t stream) {
  const float* X  = (const float*)d_in[0];
  const float* Wq = (const float*)d_in[1];
  const float* Wk = (const float*)d_in[2];
  const float* Wv = (const float*)d_in[3];
  float* Out = (float*)d_out;

  char* ws = (char*)d_ws;
  ushort* Xb  = (ushort*)(ws);                      // 16 MiB  bf16 X
  ushort* Wtb = (ushort*)(ws + 16777216);           // 1.5 MiB bf16 W^T x3
  ushort* Qb  = (ushort*)(ws + 18350080);           // 16 MiB (frag-linear Q2)
  ushort* Kb  = (ushort*)(ws + 35127296);           // 16 MiB (frag-linear K2)
  ushort* Vtb = (ushort*)(ws + 51904512);           // 16 MiB (frag-linear V2)

  cvt_x_kernel<<<2048, 256, 0, stream>>>(X, Xb);
  cvt_w_kernel<<<dim3(8, 8, 3), 256, 0, stream>>>(Wq, Wk, Wv, Wtb);
  proj_kernel<<<1536, 256, 0, stream>>>(Xb, Wtb, Qb, Kb, Vtb);
  attn_kernel<<<1024, 256, 0, stream>>>(Qb, Kb, Vtb, Out);
}